// Round 1
// baseline (219.885 us; speedup 1.0000x reference)
//
#include <hip/hip_runtime.h>
#include <math.h>

#define BN_SCALE_F 0.99999500003749969f

// x: [N=64][T=300][C=64][V=25] fp32
// pooled: [N*C=4096][T=300]
// kern:   [4096][3]
// la:     [4096][300]

// ---------------- Kernel 1: mean over V ----------------
// block = 256 threads (4 waves), each wave reduces one (n,t) chunk of 1600 floats.
__global__ __launch_bounds__(256) void pool_kernel(const float* __restrict__ x,
                                                   float* __restrict__ pooled) {
  __shared__ float buf[6400];
  int bid = blockIdx.x;  // 0..4799, each covers 4 consecutive (n,t)
  const float4* src = (const float4*)(x + (size_t)bid * 6400);
  float4* b4 = (float4*)buf;
  for (int i = threadIdx.x; i < 1600; i += 256) b4[i] = src[i];
  __syncthreads();
  int wave = threadIdx.x >> 6;
  int c = threadIdx.x & 63;
  int nt = bid * 4 + wave;
  int n = nt / 300, t = nt - n * 300;
  const float* p = buf + wave * 1600 + c * 25;
  float s = 0.f;
#pragma unroll
  for (int v = 0; v < 25; ++v) s += p[v];
  pooled[((size_t)(n * 64 + c)) * 300 + t] = s * 0.04f;
}

// ---------------- Kernel 2: G branch ----------------
// 16 rows per block; h = relu(BN*row@g_w1^T) [600], logits = h@g_w2^T [3], softmax.
__global__ __launch_bounds__(256) void g_kernel(const float* __restrict__ pooled,
                                                const float* __restrict__ g_w1,  // [600][300]
                                                const float* __restrict__ g_w2,  // [3][600]
                                                float* __restrict__ kern) {      // [4096][3]
  __shared__ float rows[16][304];
  __shared__ float hbuf[16][600];
  __shared__ float lg[16][3];
  int r0 = blockIdx.x * 16;
  for (int i = threadIdx.x; i < 16 * 300; i += 256) {
    int r = i / 300, t = i - r * 300;
    rows[r][t] = pooled[(size_t)(r0 + r) * 300 + t];
  }
  __syncthreads();
  for (int jj = 0; jj < 3; ++jj) {
    int j = threadIdx.x + jj * 256;
    if (j < 600) {
      float acc[16];
#pragma unroll
      for (int r = 0; r < 16; ++r) acc[r] = 0.f;
      const float4* w4 = (const float4*)(g_w1 + (size_t)j * 300);
      for (int t4 = 0; t4 < 75; ++t4) {
        float4 wv = w4[t4];
#pragma unroll
        for (int r = 0; r < 16; ++r) {
          float4 rv = *(const float4*)(&rows[r][t4 * 4]);
          acc[r] = fmaf(rv.x, wv.x, acc[r]);
          acc[r] = fmaf(rv.y, wv.y, acc[r]);
          acc[r] = fmaf(rv.z, wv.z, acc[r]);
          acc[r] = fmaf(rv.w, wv.w, acc[r]);
        }
      }
#pragma unroll
      for (int r = 0; r < 16; ++r) {
        float hv = acc[r] * BN_SCALE_F;
        hbuf[r][j] = hv > 0.f ? hv : 0.f;
      }
    }
  }
  __syncthreads();
  if (threadIdx.x < 48) {
    int r = threadIdx.x / 3;
    int k = threadIdx.x - r * 3;
    const float4* hv = (const float4*)(&hbuf[r][0]);
    const float4* wv = (const float4*)(g_w2 + k * 600);
    float s = 0.f;
    for (int q = 0; q < 150; ++q) {
      float4 a = hv[q], b = wv[q];
      s = fmaf(a.x, b.x, fmaf(a.y, b.y, fmaf(a.z, b.z, fmaf(a.w, b.w, s))));
    }
    lg[r][k] = s;
  }
  __syncthreads();
  if (threadIdx.x < 16) {
    int r = threadIdx.x;
    float a = lg[r][0], b = lg[r][1], cc = lg[r][2];
    float m = fmaxf(a, fmaxf(b, cc));
    float ea = expf(a - m), eb = expf(b - m), ec = expf(cc - m);
    float inv = 1.f / (ea + eb + ec);
    size_t o = (size_t)(r0 + r) * 3;
    kern[o] = ea * inv;
    kern[o + 1] = eb * inv;
    kern[o + 2] = ec * inv;
  }
}

// ---------------- Kernel 3: L branch ----------------
// One block per n. conv1d(C->16,K=3,pad=1) + relu + 1x1 conv(16->64) + sigmoid.
__global__ __launch_bounds__(320) void l_kernel(const float* __restrict__ pooled,
                                                const float* __restrict__ l_w1,  // [16][64][3]
                                                const float* __restrict__ l_w2,  // [64][16]
                                                float* __restrict__ la) {        // [4096][300]
  __shared__ float p[64][304];   // tp in 0..301 valid; t = tp-1; edges zero
  __shared__ float z[16][300];
  __shared__ float w1s[64][48];  // [c][o*3+k]
  int n = blockIdx.x;
  for (int i = threadIdx.x; i < 3072; i += 320) {
    int k = i % 3;
    int c = (i / 3) & 63;
    int o = i / 192;
    w1s[c][o * 3 + k] = l_w1[i];
  }
  for (int i = threadIdx.x; i < 64 * 304; i += 320) {
    int c = i / 304, tp = i - c * 304;
    p[c][tp] = (tp >= 1 && tp <= 300) ? pooled[(size_t)(n * 64 + c) * 300 + (tp - 1)] : 0.f;
  }
  __syncthreads();
  int t = threadIdx.x;
  if (t < 300) {
    float acc[16];
#pragma unroll
    for (int o = 0; o < 16; ++o) acc[o] = 0.f;
    for (int c = 0; c < 64; ++c) {
      float pk[3];
      pk[0] = p[c][t];
      pk[1] = p[c][t + 1];
      pk[2] = p[c][t + 2];
      const float4* wv4 = (const float4*)(&w1s[c][0]);
      float w[48];
#pragma unroll
      for (int q = 0; q < 12; ++q) {
        float4 f = wv4[q];
        w[q * 4] = f.x; w[q * 4 + 1] = f.y; w[q * 4 + 2] = f.z; w[q * 4 + 3] = f.w;
      }
#pragma unroll
      for (int m = 0; m < 48; ++m) acc[m / 3] = fmaf(w[m], pk[m % 3], acc[m / 3]);
    }
#pragma unroll
    for (int o = 0; o < 16; ++o) {
      float v = acc[o] * BN_SCALE_F;
      z[o][t] = v > 0.f ? v : 0.f;
    }
  }
  __syncthreads();
  {
    int c = threadIdx.x / 5;        // 0..63
    int t4b = threadIdx.x - c * 5;  // 0..4
    const float* w2row = l_w2 + c * 16;
    float w2r[16];
#pragma unroll
    for (int o = 0; o < 16; ++o) w2r[o] = w2row[o];
    float* outp = la + ((size_t)(n * 64 + c)) * 300;
    for (int it = 0; it < 15; ++it) {
      int t4 = t4b + it * 5;  // 0..74
      float4 s = {0.f, 0.f, 0.f, 0.f};
#pragma unroll
      for (int o = 0; o < 16; ++o) {
        float4 zv = *(const float4*)(&z[o][t4 * 4]);
        float wo = w2r[o];
        s.x = fmaf(zv.x, wo, s.x);
        s.y = fmaf(zv.y, wo, s.y);
        s.z = fmaf(zv.z, wo, s.z);
        s.w = fmaf(zv.w, wo, s.w);
      }
      float4 r;
      r.x = 1.f / (1.f + expf(-s.x));
      r.y = 1.f / (1.f + expf(-s.y));
      r.z = 1.f / (1.f + expf(-s.z));
      r.w = 1.f / (1.f + expf(-s.w));
      *(float4*)(&outp[t4 * 4]) = r;
    }
  }
}

// ---------------- Kernel 4: final depthwise temporal conv ----------------
// out[n,t,c,v] = sum_k x[n,t+k-1,c,v]*la[n,c,t+k-1]*kern[n,c,k]; x read once via sliding window.
__global__ __launch_bounds__(320) void tam_final_kernel(const float* __restrict__ x,
                                                        const float* __restrict__ la,
                                                        const float* __restrict__ kern,
                                                        float* __restrict__ out) {
  int bid = blockIdx.x;
  int n = bid / 20;
  int rem = bid - n * 20;
  int part = rem / 4;  // 0..4 over cv
  int tc = rem & 3;    // 0..3 over t chunks of 75
  int cv = part * 320 + threadIdx.x;  // 0..1599
  int c = cv / 25;
  int t0 = tc * 75;
  size_t xb = (size_t)n * 480000 + cv;
  const float* lap = la + (size_t)(n * 64 + c) * 300;
  const float* kp = kern + (size_t)(n * 64 + c) * 3;
  float k0 = kp[0], k1 = kp[1], k2 = kp[2];
  float am, ac;
  if (t0 > 0)
    am = x[xb + (size_t)(t0 - 1) * 1600] * lap[t0 - 1];
  else
    am = 0.f;
  ac = x[xb + (size_t)t0 * 1600] * lap[t0];
  float* op = out + xb;
#pragma unroll 5
  for (int t = t0; t < t0 + 75; ++t) {
    float an = 0.f;
    if (t + 1 < 300) an = x[xb + (size_t)(t + 1) * 1600] * lap[t + 1];
    op[(size_t)t * 1600] = fmaf(am, k0, fmaf(ac, k1, an * k2));
    am = ac;
    ac = an;
  }
}

extern "C" void kernel_launch(void* const* d_in, const int* in_sizes, int n_in,
                              void* d_out, int out_size, void* d_ws, size_t ws_size,
                              hipStream_t stream) {
  const float* x = (const float*)d_in[0];
  const float* g_w1 = (const float*)d_in[1];
  const float* g_w2 = (const float*)d_in[2];
  const float* l_w1 = (const float*)d_in[3];
  const float* l_w2 = (const float*)d_in[4];
  float* out = (float*)d_out;
  float* ws = (float*)d_ws;
  float* pooled = ws;                    // 4096*300 = 1,228,800 floats
  float* kern = ws + 1228800;            // 4096*3   = 12,288 floats
  float* lact = ws + 1228800 + 12288;    // 4096*300 = 1,228,800 floats

  hipLaunchKernelGGL(pool_kernel, dim3(4800), dim3(256), 0, stream, x, pooled);
  hipLaunchKernelGGL(g_kernel, dim3(256), dim3(256), 0, stream, pooled, g_w1, g_w2, kern);
  hipLaunchKernelGGL(l_kernel, dim3(64), dim3(320), 0, stream, pooled, l_w1, l_w2, lact);
  hipLaunchKernelGGL(tam_final_kernel, dim3(1280), dim3(320), 0, stream, x, lact, kern, out);
}